// Round 11
// baseline (167.539 us; speedup 1.0000x reference)
//
#include <hip/hip_runtime.h>

#define Bsz 1024
#define Nn 256
#define Fdim 8
#define Eedge 1024
#define OUTC 128
#define CADV 192
#define CTOT 256
#define Ktot 32768   // Nn * OUTC
#define ASTR 40      // a_s LDS row stride in bf16 (32+8): 16B-aligned, 2-way banks
#define XSTR 24      // x_s/rw_s row stride (48 B = 12-bank stride -> 2-way, free)

typedef __attribute__((ext_vector_type(8))) short short8;
typedef __attribute__((ext_vector_type(4))) float float4v;

static __device__ inline unsigned short f2bf(float f) {
  union { float f; unsigned u; } v; v.f = f;
  unsigned r = v.u + 0x7FFFu + ((v.u >> 16) & 1u);  // round-nearest-even
  return (unsigned short)(r >> 16);
}
static __device__ inline float bf2f(unsigned short h) {
  union { unsigned u; float f; } v; v.u = ((unsigned)h) << 16;
  return v.f;
}
static __device__ inline uint4 pack8(const unsigned short* b) {
  uint4 v;
  v.x = (unsigned)b[0] | ((unsigned)b[1] << 16);
  v.y = (unsigned)b[2] | ((unsigned)b[3] << 16);
  v.z = (unsigned)b[4] | ((unsigned)b[5] << 16);
  v.w = (unsigned)b[6] | ((unsigned)b[7] << 16);
  return v;
}
// async 16B global->LDS DMA; lds dest = wave-uniform base + lane*16
static __device__ inline void gll16(const void* g, void* l) {
  __builtin_amdgcn_global_load_lds(
      (const __attribute__((address_space(1))) void*)g,
      (__attribute__((address_space(3))) void*)l, 16, 0, 0);
}

// ---------------------------------------------------------------------------
// K1: tail x16 (theta + S scatter + feat0 b=0 correction) + wt transpose.
// R20: wt words are stored at SWIZZLED positions p = w ^ ((w>>3)&7) (an
// involution: the mask uses only bits 3-5, XOR touches bits 0-2). K2's
// global_load_lds writes LDS linearly, so the swizzle lands in LDS and the
// bF ds_read applies the same XOR -> 16 lm-lanes spread over all 8 bank
// slots (2-way = free; unswizzled unpadded would be 8-way).
// ---------------------------------------------------------------------------
__global__ __launch_bounds__(256) void prep_feat_kernel(
    const float* __restrict__ x, const int* __restrict__ ei,
    const float* __restrict__ w1, const float* __restrict__ b1,
    const float* __restrict__ w2, const float* __restrict__ b2,
    const float* __restrict__ rootw, const float* __restrict__ convb,
    const float* __restrict__ advw, const float* __restrict__ v1w,
    unsigned short* __restrict__ wt, unsigned short* __restrict__ feat0)
{
  __shared__ __align__(16) char smem[20480];
  int bid = blockIdx.x, t = threadIdx.x;

  if (bid < 16) {
    // ---- tail x16: theta slice + redundant scatter S + feat0 o-slice ----
    float* fs   = (float*)smem;
    float* h_s  = fs;            // 64
    float* rw_s = fs + 64;       // 64
    float* th_s = fs + 128;      // 64
    float* pt_s = fs + 192;      // 256
    float* S_s  = fs + 448;      // 2048
    int*   flag = (int*)(fs + 2496);
    int obase = bid * 8;

    if (t < 64) {
      h_s[t]  = fmaxf(w1[t] + b1[t], 0.f);
      rw_s[t] = rootw[(t >> 3) * OUTC + obase + (t & 7)];
    }
    for (int i = t; i < Nn * Fdim; i += 256) S_s[i] = 0.f;
    if (t == 0) {
      int z = 0;
      for (int i = 1; i < 16; i += 2) z |= ei[i];
      *flag = (z == 0);  // little-endian int64 detection
    }
    __syncthreads();
    int is64 = *flag;

    {  // theta slice: 64 cols x 64-deep reduction across 4 waves
      int l = t & 63, g = t >> 6;
      int c = (l >> 3) * 128 + obase + (l & 7);
      float p = 0.f;
#pragma unroll
      for (int j = 0; j < 16; ++j)
        p += h_s[g * 16 + j] * w2[(size_t)(g * 16 + j) * 1024 + c];
      pt_s[t] = p;
    }
    int srcs[4], tgts[4];
#pragma unroll
    for (int q = 0; q < 4; ++q) {
      int e = t + q * 256;
      if (is64) { srcs[q] = ei[2 * e]; tgts[q] = ei[2 * (Eedge + e)]; }
      else      { srcs[q] = ei[e];     tgts[q] = ei[Eedge + e]; }
      srcs[q] &= 255; tgts[q] &= 255;
    }
    __syncthreads();
    if (t < 64) {
      int c = (t >> 3) * 128 + obase + (t & 7);
      th_s[t] = b2[c] + pt_s[t] + pt_s[t + 64] + pt_s[t + 128] + pt_s[t + 192];
    }
#pragma unroll
    for (int q = 0; q < 4; ++q) {
      const float* xp = x + srcs[q] * Fdim;
#pragma unroll
      for (int f = 0; f < Fdim; ++f)
        atomicAdd(&S_s[tgts[q] * Fdim + f], xp[f]);
    }
    __syncthreads();
    {  // feat0 slice: thread t = node n, 8 o-columns
      int n = t;
      const float* xp = x + n * Fdim;
      float4 xa = *(const float4*)xp;
      float4 xb = *(const float4*)(xp + 4);
      float xv[8] = {xa.x, xa.y, xa.z, xa.w, xb.x, xb.y, xb.z, xb.w};
      float sv[8];
#pragma unroll
      for (int f = 0; f < 8; ++f) sv[f] = S_s[n * Fdim + f];
      unsigned short buf[8];
#pragma unroll
      for (int oi = 0; oi < 8; ++oi) {
        float z = convb[obase + oi];
#pragma unroll
        for (int f = 0; f < 8; ++f)
          z += xv[f] * rw_s[f * 8 + oi] + sv[f] * th_s[f * 8 + oi];
        buf[oi] = f2bf(fmaxf(z, 0.f));
      }
      *(uint4*)(feat0 + (size_t)n * OUTC + obase) = pack8(buf);
    }
  } else {
    // ---- wt transpose: 32-deep load batch, LDS-staged, swizzled flush ----
    unsigned short* st = (unsigned short*)smem;  // 20 KB
    int kt = bid - 16, c = t;
    const float* src; int stride, col;
    if (c < CADV) { src = advw; stride = CADV; col = c; }
    else          { src = v1w;  stride = 64;   col = c - CADV; }
    float v[32];
#pragma unroll
    for (int i = 0; i < 32; ++i)
      v[i] = src[(size_t)(kt * 32 + i) * stride + col];
    unsigned short bv[32];
#pragma unroll
    for (int i = 0; i < 32; ++i) bv[i] = f2bf(v[i]);
#pragma unroll
    for (int p = 0; p < 4; ++p)
      *(uint4*)(st + c * ASTR + p * 8) = pack8(bv + p * 8);
    __syncthreads();
    uint4* dst = (uint4*)(wt + (size_t)kt * (CTOT * 32));
    for (int r = 0; r < 4; ++r) {
      int w = r * 256 + c;            // write position: lane-consecutive
      int s = w ^ ((w >> 3) & 7);     // logical word that lands here
      dst[w] = *(const uint4*)(st + (s >> 2) * ASTR + (s & 3) * 8);
    }
  }
}

// ---------------------------------------------------------------------------
// K2 (R20): fused-A MFMA GEMM with ASYNC B-staging.
// B tile kk+1 is DMA'd global->LDS via global_load_lds (16B/lane), issued
// right AFTER iter kk's barrier (its target buffer's readers all passed
// that barrier); the NEXT barrier's vmcnt(0) drain is the completion point
// -> ~3K cyc of MFMA+A-gen cover the latency. Deletes the per-iter
// global->VGPR->ds_write round-trip (Common-mistake #1; m97: width-16
// global_load_lds was +67% on this exact 2-barrier structure).
// b_s is unpadded (DMA is linear); bank conflicts fixed by the wt-side
// XOR swizzle + same XOR on the bF ds_read (rule #21).
// ---------------------------------------------------------------------------
__global__ __launch_bounds__(512, 2) void gemm_mfma(
    const float* __restrict__ x, const unsigned short* __restrict__ wt,
    const float* __restrict__ rootw, const float* __restrict__ convb,
    const unsigned short* __restrict__ feat0, float* __restrict__ part,
    int iters, int ns)
{
  __shared__ __align__(16) short a_s[2][128 * ASTR];   // 20 KB
  __shared__ __align__(16) short b_s[2][256 * 32];     // 32 KB (linear, DMA)
  __shared__ __align__(16) short x_s[2][128 * XSTR];   // 12 KB
  __shared__ __align__(16) short rw_s[128 * XSTR];     // 6 KB
  __shared__ float convb_s[128];                       // 0.5 KB
  int t = threadIdx.x;
  int ch = blockIdx.x;   // K chunk (XCD = ch%8; 8 mb-blocks share its L2 set)
  int mb = blockIdx.y;   // 0..7
  int wave = t >> 6, lane = t & 63;
  int wm = wave >> 2, wn = wave & 3;   // 2 x 4 wave grid
  int lm = lane & 15, lq = lane >> 4;

  float4v acc[4][4];
#pragma unroll
  for (int i = 0; i < 4; ++i)
#pragma unroll
    for (int j = 0; j < 4; ++j) acc[i][j] = (float4v)0.f;

  int kt0 = ch * iters;
  int iters4 = iters >> 2;          // nodes in this chunk
  int n0 = ch * iters4;             // first node

  // ---- prologue staging ----
  if (t < 128) {
    float wv[8];
#pragma unroll
    for (int f = 0; f < 8; ++f) wv[f] = rootw[f * OUTC + t];
    unsigned short wh[8], wl[8];
#pragma unroll
    for (int f = 0; f < 8; ++f) {
      wh[f] = f2bf(wv[f]);
      wl[f] = f2bf(wv[f] - bf2f(wh[f]));
    }
    *(uint4*)(rw_s + t * XSTR)     = pack8(wh);
    *(uint4*)(rw_s + t * XSTR + 8) = pack8(wl);
    convb_s[t] = convb[t];
  }
  int xr = (t & 255) >> 1, xh = t & 1;
  const float* xgb = x + ((size_t)(mb * 128 + xr) * Nn) * Fdim + xh * 4;
  if (t < 256) {
    float4 xv = *(const float4*)(xgb + (size_t)n0 * Fdim);
    float xa[4] = {xv.x, xv.y, xv.z, xv.w};
    unsigned short hh[4], ll[4];
#pragma unroll
    for (int f = 0; f < 4; ++f) {
      hh[f] = f2bf(xa[f]);
      ll[f] = f2bf(xa[f] - bf2f(hh[f]));
    }
    uint2 dh, dl;
    dh.x = (unsigned)hh[0] | ((unsigned)hh[1] << 16);
    dh.y = (unsigned)hh[2] | ((unsigned)hh[3] << 16);
    dl.x = (unsigned)ll[0] | ((unsigned)ll[1] << 16);
    dl.y = (unsigned)ll[2] | ((unsigned)ll[3] << 16);
    *(uint2*)(x_s[0] + xr * XSTR + xh * 4)     = dh;
    *(uint2*)(x_s[0] + xr * XSTR + 8 + xh * 4) = dl;
  }
  // issue async DMA for B tile 0 (drained by the first in-loop barrier)
  {
    const uint4* gq = (const uint4*)wt + (size_t)kt0 * 1024;
    gll16(gq + t,       (char*)b_s[0] + wave * 1024);
    gll16(gq + t + 512, (char*)b_s[0] + (wave + 8) * 1024);
  }
  __syncthreads();

  // stage A-subtile for iter 0 (g=0, node n0, x_s[0] -> a_s[0])
  {
    int bloc = wave * 16 + lm;
    short8 xf = (short8)0;
    if (lq == 0 || lq == 2) xf = *(const short8*)(x_s[0] + bloc * XSTR);
    else if (lq == 1)       xf = *(const short8*)(x_s[0] + bloc * XSTR + 8);
#pragma unroll
    for (int tt = 0; tt < 2; ++tt) {
      int ot = tt;                       // g=0
      short8 wf = (short8)0;
      if (lq <= 1)      wf = *(const short8*)(rw_s + (ot * 16 + lm) * XSTR);
      else if (lq == 2) wf = *(const short8*)(rw_s + (ot * 16 + lm) * XSTR + 8);
      float4v c = __builtin_amdgcn_mfma_f32_16x16x32_bf16(wf, xf, (float4v)0.f, 0, 0, 0);
      int o0 = ot * 16 + lq * 4;
      float4 cb = *(const float4*)(convb_s + o0);
      unsigned d0 = (unsigned)f2bf(fmaxf(c[0] + cb.x, 0.f)) |
                    ((unsigned)f2bf(fmaxf(c[1] + cb.y, 0.f)) << 16);
      unsigned d1 = (unsigned)f2bf(fmaxf(c[2] + cb.z, 0.f)) |
                    ((unsigned)f2bf(fmaxf(c[3] + cb.w, 0.f)) << 16);
      if (mb == 0 && bloc == 0) {
        const unsigned* f0p = (const unsigned*)(feat0 + ((size_t)n0 * OUTC + o0));
        d0 = f0p[0]; d1 = f0p[1];
      }
      uint2 dd; dd.x = d0; dd.y = d1;
      *(uint2*)(a_s[0] + bloc * ASTR + tt * 16 + lq * 4) = dd;
    }
  }

  float4 xpf = {0.f, 0.f, 0.f, 0.f};

  for (int kk = 0; kk < iters; ++kk) {
    int g = kk & 3, grp = kk >> 2;
    if (g == 3 && grp + 1 < iters4 && t < 256) {
      float xa[4] = {xpf.x, xpf.y, xpf.z, xpf.w};
      unsigned short hh[4], ll[4];
#pragma unroll
      for (int f = 0; f < 4; ++f) {
        hh[f] = f2bf(xa[f]);
        ll[f] = f2bf(xa[f] - bf2f(hh[f]));
      }
      uint2 dh, dl;
      dh.x = (unsigned)hh[0] | ((unsigned)hh[1] << 16);
      dh.y = (unsigned)hh[2] | ((unsigned)hh[3] << 16);
      dl.x = (unsigned)ll[0] | ((unsigned)ll[1] << 16);
      dl.y = (unsigned)ll[2] | ((unsigned)ll[3] << 16);
      short* xd = x_s[(grp + 1) & 1];
      *(uint2*)(xd + xr * XSTR + xh * 4)     = dh;
      *(uint2*)(xd + xr * XSTR + 8 + xh * 4) = dl;
    }
    __syncthreads();   // drains DMA(tile kk) + syncs a_s/x_s writes

    // issue async DMA for tile kk+1 (its buffer's readers passed the barrier)
    if (kk + 1 < iters) {
      const uint4* gq = (const uint4*)wt + (size_t)(kt0 + kk + 1) * 1024;
      char* bd = (char*)b_s[(kk + 1) & 1];
      gll16(gq + t,       bd + wave * 1024);
      gll16(gq + t + 512, bd + (wave + 8) * 1024);
    }
    if (g == 0 && grp + 1 < iters4 && t < 256)
      xpf = *(const float4*)(xgb + (size_t)(n0 + grp + 1) * Fdim);

    // main MFMA on tile kk: bF via swizzled ds_read, aF from a_s
    short* ab = a_s[kk & 1];
    const char* bb = (const char*)b_s[kk & 1];
    short8 aF[4];
#pragma unroll
    for (int i = 0; i < 4; ++i)
      aF[i] = *(const short8*)(ab + (wm * 64 + i * 16 + lm) * ASTR + lq * 8);
#pragma unroll
    for (int j = 0; j < 4; ++j) {
      int r = wn * 64 + j * 16 + lm;
      int lb = (r * 64 + lq * 16) ^ (((r >> 1) & 7) << 4);
      short8 bF = *(const short8*)(bb + lb);
#pragma unroll
      for (int i = 0; i < 4; ++i)
        acc[i][j] = __builtin_amdgcn_mfma_f32_16x16x32_bf16(bF, aF[i], acc[i][j], 0, 0, 0);
    }

    // stage A-subtile for iter kk+1 into the other buffer
    if (kk + 1 < iters) {
      int kn = kk + 1;
      int g2 = kn & 3, grp2 = kn >> 2;
      const short* xs = x_s[grp2 & 1];
      int node2 = n0 + grp2;
      short* ad = a_s[kn & 1];
      int bloc = wave * 16 + lm;
      short8 xf = (short8)0;
      if (lq == 0 || lq == 2) xf = *(const short8*)(xs + bloc * XSTR);
      else if (lq == 1)       xf = *(const short8*)(xs + bloc * XSTR + 8);
#pragma unroll
      for (int tt = 0; tt < 2; ++tt) {
        int ot = g2 * 2 + tt;
        short8 wf = (short8)0;
        if (lq <= 1)      wf = *(const short8*)(rw_s + (ot * 16 + lm) * XSTR);
        else if (lq == 2) wf = *(const short8*)(rw_s + (ot * 16 + lm) * XSTR + 8);
        float4v c = __builtin_amdgcn_mfma_f32_16x16x32_bf16(wf, xf, (float4v)0.f, 0, 0, 0);
        int o0 = ot * 16 + lq * 4;
        float4 cb = *(const float4*)(convb_s + o0);
        unsigned d0 = (unsigned)f2bf(fmaxf(c[0] + cb.x, 0.f)) |
                      ((unsigned)f2bf(fmaxf(c[1] + cb.y, 0.f)) << 16);
        unsigned d1 = (unsigned)f2bf(fmaxf(c[2] + cb.z, 0.f)) |
                      ((unsigned)f2bf(fmaxf(c[3] + cb.w, 0.f)) << 16);
        if (mb == 0 && bloc == 0) {
          const unsigned* f0p = (const unsigned*)(feat0 + ((size_t)node2 * OUTC + o0));
          d0 = f0p[0]; d1 = f0p[1];
        }
        uint2 dd; dd.x = d0; dd.y = d1;
        *(uint2*)(ad + bloc * ASTR + tt * 16 + lq * 4) = dd;
      }
    }
  }

  // epilogue: part layout [b][ch][c]; per-lane dwordx4
  float* pb = part + ((size_t)(mb * 128) * ns + ch) * CTOT;
#pragma unroll
  for (int i = 0; i < 4; ++i) {
    int m = wm * 64 + i * 16 + lm;
#pragma unroll
    for (int j = 0; j < 4; ++j) {
      int c = wn * 64 + j * 16 + lq * 4;
      *(float4v*)(pb + (size_t)m * ns * CTOT + c) = acc[i][j];
    }
  }
}

// ---------------------------------------------------------------------------
// K3 (R19-proven): float4-vectorized split-K reduction + LDS combine,
// then biases+relu, val MLP, dueling combine.
// ---------------------------------------------------------------------------
__global__ __launch_bounds__(256) void final_kernel(
    const float* __restrict__ part, int ns,
    const float* __restrict__ advb, const float* __restrict__ v1b,
    const float* __restrict__ v2w, const float* __restrict__ v2b,
    const float* __restrict__ v3w, const float* __restrict__ v3b,
    float* __restrict__ out)
{
  __shared__ float4v red_s[4][64];   // 4 KB
  __shared__ float adv_s[CADV];
  __shared__ float v1_s[64];
  __shared__ float val2_s[64];
  __shared__ float val3_s[64];
  int b = blockIdx.x, t = threadIdx.x;
  int q = t & 63, r0 = t >> 6;       // col-quad, row-group
  const float4v* p4 = (const float4v*)(part + (size_t)b * ns * CTOT);
  float4v s4 = (float4v)0.f;
  for (int i = r0; i < ns; i += 4) s4 += p4[i * 64 + q];
  red_s[r0][q] = s4;
  __syncthreads();
  float s;
  {
    const float* rs = (const float*)red_s;   // [r][256] floats
    s = rs[t] + rs[256 + t] + rs[512 + t] + rs[768 + t];
  }
  if (t < CADV) adv_s[t] = fmaxf(s + advb[t], 0.f);
  else          v1_s[t - CADV] = fmaxf(s + v1b[t - CADV], 0.f);
  __syncthreads();
  if (t < 64) {
    float a = v2b[t];
#pragma unroll
    for (int i = 0; i < 64; ++i) a += v1_s[i] * v2w[i * 64 + t];
    val2_s[t] = fmaxf(a, 0.f);
  }
  __syncthreads();
  if (t < 64) {
    float a = v3b[t];
#pragma unroll
    for (int j = 0; j < 64; ++j) a += val2_s[j] * v3w[j * 64 + t];
    val3_s[t] = a;
  }
  __syncthreads();
  if (t < CADV) {
    int d = t / 3;
    float mean = (adv_s[d * 3] + adv_s[d * 3 + 1] + adv_s[d * 3 + 2]) * (1.f / 3.f);
    out[(size_t)b * CADV + t] = val3_s[d] + adv_s[t] - mean;
  }
}

extern "C" void kernel_launch(void* const* d_in, const int* in_sizes, int n_in,
                              void* d_out, int out_size, void* d_ws, size_t ws_size,
                              hipStream_t stream)
{
  (void)in_sizes; (void)n_in; (void)out_size;
  const float* x     = (const float*)d_in[0];
  const int*   ei    = (const int*)d_in[1];
  const float* w1    = (const float*)d_in[2];
  const float* b1    = (const float*)d_in[3];
  const float* w2    = (const float*)d_in[4];
  const float* b2    = (const float*)d_in[5];
  const float* rootw = (const float*)d_in[6];
  const float* convb = (const float*)d_in[7];
  const float* advw  = (const float*)d_in[8];
  const float* advb  = (const float*)d_in[9];
  const float* v1w   = (const float*)d_in[10];
  const float* v1b   = (const float*)d_in[11];
  const float* v2w   = (const float*)d_in[12];
  const float* v2b   = (const float*)d_in[13];
  const float* v3w   = (const float*)d_in[14];
  const float* v3b   = (const float*)d_in[15];
  float* out = (float*)d_out;

  const size_t f0B = 131072;                    // feat0 64 KB (padded)
  const size_t wtB = (size_t)Ktot * CTOT * 2;   // 16.8 MB

  int NS = 64;
  while (NS > 8 && f0B + wtB + (size_t)NS * Bsz * CTOT * 4 > ws_size)
    NS >>= 1;

  unsigned short* feat0 = (unsigned short*)d_ws;
  unsigned short* wtp   = (unsigned short*)((char*)d_ws + f0B);
  float* part = (float*)((char*)d_ws + f0B + wtB);

  prep_feat_kernel<<<1040, 256, 0, stream>>>(x, ei, w1, b1, w2, b2, rootw,
                                             convb, advw, v1w, wtp, feat0);
  gemm_mfma<<<dim3(NS, 8), 512, 0, stream>>>(x, wtp, rootw, convb, feat0, part,
                                             1024 / NS, NS);
  final_kernel<<<Bsz, 256, 0, stream>>>(part, NS, advb, v1b, v2w, v2b, v3w, v3b, out);
}

// Round 12
// 166.398 us; speedup vs baseline: 1.0069x; 1.0069x over previous
//
#include <hip/hip_runtime.h>

#define Bsz 1024
#define Nn 256
#define Fdim 8
#define Eedge 1024
#define OUTC 128
#define CADV 192
#define CTOT 256
#define Ktot 32768   // Nn * OUTC
#define ASTR 40      // a_s/b_s LDS row stride in bf16 (32+8): 16B-aligned
#define XSTR 24      // x_s/rw_s row stride (48 B = 12-bank stride -> 2-way, free)

typedef __attribute__((ext_vector_type(8))) short short8;
typedef __attribute__((ext_vector_type(4))) float float4v;

static __device__ inline unsigned short f2bf(float f) {
  union { float f; unsigned u; } v; v.f = f;
  unsigned r = v.u + 0x7FFFu + ((v.u >> 16) & 1u);  // round-nearest-even
  return (unsigned short)(r >> 16);
}
static __device__ inline float bf2f(unsigned short h) {
  union { unsigned u; float f; } v; v.u = ((unsigned)h) << 16;
  return v.f;
}
static __device__ inline uint4 pack8(const unsigned short* b) {
  uint4 v;
  v.x = (unsigned)b[0] | ((unsigned)b[1] << 16);
  v.y = (unsigned)b[2] | ((unsigned)b[3] << 16);
  v.z = (unsigned)b[4] | ((unsigned)b[5] << 16);
  v.w = (unsigned)b[6] | ((unsigned)b[7] << 16);
  return v;
}
// R21: HW packed f32->bf16 RNE convert: dst = bf(a) | bf(b)<<16, ONE VALU op.
// The manual f2bf bit-RNE (~4-5 VALU each) is not pattern-matched by hipcc;
// identical rounding for finite inputs -> bit-identical results.
static __device__ inline unsigned cvtpk(float a, float b) {
  unsigned r;
  asm("v_cvt_pk_bf16_f32 %0, %1, %2" : "=v"(r) : "v"(a), "v"(b));
  return r;
}
static __device__ inline float hi_of(unsigned p)  {  // bf2f(low half)
  union { unsigned u; float f; } v; v.u = p << 16; return v.f;
}
static __device__ inline float hi2_of(unsigned p) {  // bf2f(high half)
  union { unsigned u; float f; } v; v.u = p & 0xFFFF0000u; return v.f;
}

// ---------------------------------------------------------------------------
// K1 (R13-proven): tail x16 (theta + S scatter + feat0 b=0 correction)
// + wt transpose (linear layout; K2 LDS-stages it).
// ---------------------------------------------------------------------------
__global__ __launch_bounds__(256) void prep_feat_kernel(
    const float* __restrict__ x, const int* __restrict__ ei,
    const float* __restrict__ w1, const float* __restrict__ b1,
    const float* __restrict__ w2, const float* __restrict__ b2,
    const float* __restrict__ rootw, const float* __restrict__ convb,
    const float* __restrict__ advw, const float* __restrict__ v1w,
    unsigned short* __restrict__ wt, unsigned short* __restrict__ feat0)
{
  __shared__ __align__(16) char smem[20480];
  int bid = blockIdx.x, t = threadIdx.x;

  if (bid < 16) {
    // ---- tail x16: theta slice + redundant scatter S + feat0 o-slice ----
    float* fs   = (float*)smem;
    float* h_s  = fs;            // 64
    float* rw_s = fs + 64;       // 64
    float* th_s = fs + 128;      // 64
    float* pt_s = fs + 192;      // 256
    float* S_s  = fs + 448;      // 2048
    int*   flag = (int*)(fs + 2496);
    int obase = bid * 8;

    if (t < 64) {
      h_s[t]  = fmaxf(w1[t] + b1[t], 0.f);
      rw_s[t] = rootw[(t >> 3) * OUTC + obase + (t & 7)];
    }
    for (int i = t; i < Nn * Fdim; i += 256) S_s[i] = 0.f;
    if (t == 0) {
      int z = 0;
      for (int i = 1; i < 16; i += 2) z |= ei[i];
      *flag = (z == 0);  // little-endian int64 detection
    }
    __syncthreads();
    int is64 = *flag;

    {  // theta slice: 64 cols x 64-deep reduction across 4 waves
      int l = t & 63, g = t >> 6;
      int c = (l >> 3) * 128 + obase + (l & 7);
      float p = 0.f;
#pragma unroll
      for (int j = 0; j < 16; ++j)
        p += h_s[g * 16 + j] * w2[(size_t)(g * 16 + j) * 1024 + c];
      pt_s[t] = p;
    }
    int srcs[4], tgts[4];
#pragma unroll
    for (int q = 0; q < 4; ++q) {
      int e = t + q * 256;
      if (is64) { srcs[q] = ei[2 * e]; tgts[q] = ei[2 * (Eedge + e)]; }
      else      { srcs[q] = ei[e];     tgts[q] = ei[Eedge + e]; }
      srcs[q] &= 255; tgts[q] &= 255;
    }
    __syncthreads();
    if (t < 64) {
      int c = (t >> 3) * 128 + obase + (t & 7);
      th_s[t] = b2[c] + pt_s[t] + pt_s[t + 64] + pt_s[t + 128] + pt_s[t + 192];
    }
#pragma unroll
    for (int q = 0; q < 4; ++q) {
      const float* xp = x + srcs[q] * Fdim;
#pragma unroll
      for (int f = 0; f < Fdim; ++f)
        atomicAdd(&S_s[tgts[q] * Fdim + f], xp[f]);
    }
    __syncthreads();
    {  // feat0 slice: thread t = node n, 8 o-columns
      int n = t;
      const float* xp = x + n * Fdim;
      float4 xa = *(const float4*)xp;
      float4 xb = *(const float4*)(xp + 4);
      float xv[8] = {xa.x, xa.y, xa.z, xa.w, xb.x, xb.y, xb.z, xb.w};
      float sv[8];
#pragma unroll
      for (int f = 0; f < 8; ++f) sv[f] = S_s[n * Fdim + f];
      unsigned short buf[8];
#pragma unroll
      for (int oi = 0; oi < 8; ++oi) {
        float z = convb[obase + oi];
#pragma unroll
        for (int f = 0; f < 8; ++f)
          z += xv[f] * rw_s[f * 8 + oi] + sv[f] * th_s[f * 8 + oi];
        buf[oi] = f2bf(fmaxf(z, 0.f));
      }
      *(uint4*)(feat0 + (size_t)n * OUTC + obase) = pack8(buf);
    }
  } else {
    // ---- wt transpose: 32-deep load batch, LDS-staged, coalesced flush ----
    unsigned short* st = (unsigned short*)smem;  // 20 KB
    int kt = bid - 16, c = t;
    const float* src; int stride, col;
    if (c < CADV) { src = advw; stride = CADV; col = c; }
    else          { src = v1w;  stride = 64;   col = c - CADV; }
    float v[32];
#pragma unroll
    for (int i = 0; i < 32; ++i)
      v[i] = src[(size_t)(kt * 32 + i) * stride + col];
    unsigned pk[16];
#pragma unroll
    for (int i = 0; i < 16; ++i) pk[i] = cvtpk(v[2 * i], v[2 * i + 1]);
#pragma unroll
    for (int p = 0; p < 4; ++p) {
      uint4 w4; w4.x = pk[p * 4]; w4.y = pk[p * 4 + 1];
      w4.z = pk[p * 4 + 2]; w4.w = pk[p * 4 + 3];
      *(uint4*)(st + c * ASTR + p * 8) = w4;
    }
    __syncthreads();
    uint4* dst = (uint4*)(wt + (size_t)kt * (CTOT * 32));
    for (int r = 0; r < 4; ++r) {
      int s = r * 256 + c;        // lane-consecutive -> coalesced
      dst[s] = *(const uint4*)(st + (s >> 2) * ASTR + (s & 3) * 8);
    }
  }
}

// ---------------------------------------------------------------------------
// K2 (R21): R19's proven structure (LDS-staged B dbuf, pre-barrier prefetch,
// single barrier/iter, fused A-gen) with ALL hot-path f2bf pairs replaced by
// v_cvt_pk_bf16_f32 (1 VALU per 2 converts vs ~9). A-gen ~20->10 VALU/tt;
// x-staging ~40->12. Rounding identical (RNE) -> bit-identical output.
// ---------------------------------------------------------------------------
__global__ __launch_bounds__(512, 2) void gemm_mfma(
    const float* __restrict__ x, const unsigned short* __restrict__ wt,
    const float* __restrict__ rootw, const float* __restrict__ convb,
    const unsigned short* __restrict__ feat0, float* __restrict__ part,
    int iters, int ns)
{
  __shared__ short a_s[2][128 * ASTR];   // 20 KB
  __shared__ short b_s[2][256 * ASTR];   // 40 KB
  __shared__ short x_s[2][128 * XSTR];   // 12 KB [b][xh0..7 | xl0..7 | pad]
  __shared__ short rw_s[128 * XSTR];     // 6 KB  [o][wh0..7 | wl0..7 | pad]
  __shared__ float convb_s[128];         // 0.5 KB
  int t = threadIdx.x;
  int ch = blockIdx.x;   // K chunk (XCD = ch%8; 8 mb-blocks share its L2 set)
  int mb = blockIdx.y;   // 0..7
  int wave = t >> 6, lane = t & 63;
  int wm = wave >> 2, wn = wave & 3;   // 2 x 4 wave grid
  int lm = lane & 15, lq = lane >> 4;

  float4v acc[4][4];
#pragma unroll
  for (int i = 0; i < 4; ++i)
#pragma unroll
    for (int j = 0; j < 4; ++j) acc[i][j] = (float4v)0.f;

  int kt0 = ch * iters;
  int iters4 = iters >> 2;          // nodes in this chunk
  int n0 = ch * iters4;             // first node
  int wr0 = (t >> 2) * ASTR + (t & 3) * 8;
  int u1 = t + 512;
  int wr1 = (u1 >> 2) * ASTR + (u1 & 3) * 8;

  // ---- prologue staging ----
  if (t < 128) {
    float wv[8];
#pragma unroll
    for (int f = 0; f < 8; ++f) wv[f] = rootw[f * OUTC + t];
    unsigned ph[4];
#pragma unroll
    for (int i = 0; i < 4; ++i) ph[i] = cvtpk(wv[2 * i], wv[2 * i + 1]);
    float wl[8];
#pragma unroll
    for (int i = 0; i < 4; ++i) {
      wl[2 * i]     = wv[2 * i]     - hi_of(ph[i]);
      wl[2 * i + 1] = wv[2 * i + 1] - hi2_of(ph[i]);
    }
    unsigned pl[4];
#pragma unroll
    for (int i = 0; i < 4; ++i) pl[i] = cvtpk(wl[2 * i], wl[2 * i + 1]);
    uint4 wh4; wh4.x = ph[0]; wh4.y = ph[1]; wh4.z = ph[2]; wh4.w = ph[3];
    uint4 wl4; wl4.x = pl[0]; wl4.y = pl[1]; wl4.z = pl[2]; wl4.w = pl[3];
    *(uint4*)(rw_s + t * XSTR)     = wh4;
    *(uint4*)(rw_s + t * XSTR + 8) = wl4;
    convb_s[t] = convb[t];
  }
  int xr = (t & 255) >> 1, xh = t & 1;
  const float* xgb = x + ((size_t)(mb * 128 + xr) * Nn) * Fdim + xh * 4;
  if (t < 256) {
    float4 xv = *(const float4*)(xgb + (size_t)n0 * Fdim);
    uint2 dh, dl;
    dh.x = cvtpk(xv.x, xv.y);
    dh.y = cvtpk(xv.z, xv.w);
    dl.x = cvtpk(xv.x - hi_of(dh.x), xv.y - hi2_of(dh.x));
    dl.y = cvtpk(xv.z - hi_of(dh.y), xv.w - hi2_of(dh.y));
    *(uint2*)(x_s[0] + xr * XSTR + xh * 4)     = dh;
    *(uint2*)(x_s[0] + xr * XSTR + 8 + xh * 4) = dl;
  }
  __syncthreads();

  // stage A-subtile for iter 0 (g=0, node n0, x_s[0] -> a_s[0])
  {
    int bloc = wave * 16 + lm;
    short8 xf = (short8)0;
    if (lq == 0 || lq == 2) xf = *(const short8*)(x_s[0] + bloc * XSTR);
    else if (lq == 1)       xf = *(const short8*)(x_s[0] + bloc * XSTR + 8);
#pragma unroll
    for (int tt = 0; tt < 2; ++tt) {
      int ot = tt;                       // g=0
      short8 wf = (short8)0;
      if (lq <= 1)      wf = *(const short8*)(rw_s + (ot * 16 + lm) * XSTR);
      else if (lq == 2) wf = *(const short8*)(rw_s + (ot * 16 + lm) * XSTR + 8);
      float4v c = __builtin_amdgcn_mfma_f32_16x16x32_bf16(wf, xf, (float4v)0.f, 0, 0, 0);
      int o0 = ot * 16 + lq * 4;
      float4 cb = *(const float4*)(convb_s + o0);
      unsigned d0 = cvtpk(fmaxf(c[0] + cb.x, 0.f), fmaxf(c[1] + cb.y, 0.f));
      unsigned d1 = cvtpk(fmaxf(c[2] + cb.z, 0.f), fmaxf(c[3] + cb.w, 0.f));
      if (mb == 0 && bloc == 0) {
        const unsigned* f0p = (const unsigned*)(feat0 + ((size_t)n0 * OUTC + o0));
        d0 = f0p[0]; d1 = f0p[1];
      }
      uint2 dd; dd.x = d0; dd.y = d1;
      *(uint2*)(a_s[0] + bloc * ASTR + tt * 16 + lq * 4) = dd;
    }
  }

  // preload B tile 0
  const uint4* gB = (const uint4*)wt + (size_t)kt0 * 1024;
  uint4 vb0 = gB[t], vb1 = gB[t + 512];
  float4 xpf = {0.f, 0.f, 0.f, 0.f};

  for (int kk = 0; kk < iters; ++kk) {
    int g = kk & 3, grp = kk >> 2;
    short* bb = b_s[kk & 1];
    *(uint4*)(bb + wr0) = vb0;
    *(uint4*)(bb + wr1) = vb1;
    if (g == 0 && grp + 1 < iters4 && t < 256)
      xpf = *(const float4*)(xgb + (size_t)(n0 + grp + 1) * Fdim);
    if (g == 3 && grp + 1 < iters4 && t < 256) {
      uint2 dh, dl;
      dh.x = cvtpk(xpf.x, xpf.y);
      dh.y = cvtpk(xpf.z, xpf.w);
      dl.x = cvtpk(xpf.x - hi_of(dh.x), xpf.y - hi2_of(dh.x));
      dl.y = cvtpk(xpf.z - hi_of(dh.y), xpf.w - hi2_of(dh.y));
      short* xd = x_s[(grp + 1) & 1];
      *(uint2*)(xd + xr * XSTR + xh * 4)     = dh;
      *(uint2*)(xd + xr * XSTR + 8 + xh * 4) = dl;
    }
    if (kk + 1 < iters) {
      const uint4* gB2 = (const uint4*)wt + (size_t)(kt0 + kk + 1) * 1024;
      vb0 = gB2[t]; vb1 = gB2[t + 512];
    }
    __syncthreads();

    // main MFMA on tile kk
    short* ab = a_s[kk & 1];
    short8 aF[4];
#pragma unroll
    for (int i = 0; i < 4; ++i)
      aF[i] = *(const short8*)(ab + (wm * 64 + i * 16 + lm) * ASTR + lq * 8);
#pragma unroll
    for (int j = 0; j < 4; ++j) {
      short8 bF = *(const short8*)(bb + (wn * 64 + j * 16 + lm) * ASTR + lq * 8);
#pragma unroll
      for (int i = 0; i < 4; ++i)
        acc[i][j] = __builtin_amdgcn_mfma_f32_16x16x32_bf16(bF, aF[i], acc[i][j], 0, 0, 0);
    }

    // stage A-subtile for iter kk+1 into the other buffer
    if (kk + 1 < iters) {
      int kn = kk + 1;
      int g2 = kn & 3, grp2 = kn >> 2;
      const short* xs = x_s[grp2 & 1];
      int node2 = n0 + grp2;
      short* ad = a_s[kn & 1];
      int bloc = wave * 16 + lm;
      short8 xf = (short8)0;
      if (lq == 0 || lq == 2) xf = *(const short8*)(xs + bloc * XSTR);
      else if (lq == 1)       xf = *(const short8*)(xs + bloc * XSTR + 8);
#pragma unroll
      for (int tt = 0; tt < 2; ++tt) {
        int ot = g2 * 2 + tt;
        short8 wf = (short8)0;
        if (lq <= 1)      wf = *(const short8*)(rw_s + (ot * 16 + lm) * XSTR);
        else if (lq == 2) wf = *(const short8*)(rw_s + (ot * 16 + lm) * XSTR + 8);
        float4v c = __builtin_amdgcn_mfma_f32_16x16x32_bf16(wf, xf, (float4v)0.f, 0, 0, 0);
        int o0 = ot * 16 + lq * 4;
        float4 cb = *(const float4*)(convb_s + o0);
        unsigned d0 = cvtpk(fmaxf(c[0] + cb.x, 0.f), fmaxf(c[1] + cb.y, 0.f));
        unsigned d1 = cvtpk(fmaxf(c[2] + cb.z, 0.f), fmaxf(c[3] + cb.w, 0.f));
        if (mb == 0 && bloc == 0) {
          const unsigned* f0p = (const unsigned*)(feat0 + ((size_t)node2 * OUTC + o0));
          d0 = f0p[0]; d1 = f0p[1];
        }
        uint2 dd; dd.x = d0; dd.y = d1;
        *(uint2*)(ad + bloc * ASTR + tt * 16 + lq * 4) = dd;
      }
    }
  }

  // epilogue: part layout [b][ch][c]; per-lane dwordx4
  float* pb = part + ((size_t)(mb * 128) * ns + ch) * CTOT;
#pragma unroll
  for (int i = 0; i < 4; ++i) {
    int m = wm * 64 + i * 16 + lm;
#pragma unroll
    for (int j = 0; j < 4; ++j) {
      int c = wn * 64 + j * 16 + lq * 4;
      *(float4v*)(pb + (size_t)m * ns * CTOT + c) = acc[i][j];
    }
  }
}

// ---------------------------------------------------------------------------
// K3 (R19-proven): float4-vectorized split-K reduction + LDS combine,
// then biases+relu, val MLP, dueling combine.
// ---------------------------------------------------------------------------
__global__ __launch_bounds__(256) void final_kernel(
    const float* __restrict__ part, int ns,
    const float* __restrict__ advb, const float* __restrict__ v1b,
    const float* __restrict__ v2w, const float* __restrict__ v2b,
    const float* __restrict__ v3w, const float* __restrict__ v3b,
    float* __restrict__ out)
{
  __shared__ float4v red_s[4][64];   // 4 KB
  __shared__ float adv_s[CADV];
  __shared__ float v1_s[64];
  __shared__ float val2_s[64];
  __shared__ float val3_s[64];
  int b = blockIdx.x, t = threadIdx.x;
  int q = t & 63, r0 = t >> 6;       // col-quad, row-group
  const float4v* p4 = (const float4v*)(part + (size_t)b * ns * CTOT);
  float4v s4 = (float4v)0.f;
  for (int i = r0; i < ns; i += 4) s4 += p4[i * 64 + q];
  red_s[r0][q] = s4;
  __syncthreads();
  float s;
  {
    const float* rs = (const float*)red_s;   // [r][256] floats
    s = rs[t] + rs[256 + t] + rs[512 + t] + rs[768 + t];
  }
  if (t < CADV) adv_s[t] = fmaxf(s + advb[t], 0.f);
  else          v1_s[t - CADV] = fmaxf(s + v1b[t - CADV], 0.f);
  __syncthreads();
  if (t < 64) {
    float a = v2b[t];
#pragma unroll
    for (int i = 0; i < 64; ++i) a += v1_s[i] * v2w[i * 64 + t];
    val2_s[t] = fmaxf(a, 0.f);
  }
  __syncthreads();
  if (t < 64) {
    float a = v3b[t];
#pragma unroll
    for (int j = 0; j < 64; ++j) a += val2_s[j] * v3w[j * 64 + t];
    val3_s[t] = a;
  }
  __syncthreads();
  if (t < CADV) {
    int d = t / 3;
    float mean = (adv_s[d * 3] + adv_s[d * 3 + 1] + adv_s[d * 3 + 2]) * (1.f / 3.f);
    out[(size_t)b * CADV + t] = val3_s[d] + adv_s[t] - mean;
  }
}

extern "C" void kernel_launch(void* const* d_in, const int* in_sizes, int n_in,
                              void* d_out, int out_size, void* d_ws, size_t ws_size,
                              hipStream_t stream)
{
  (void)in_sizes; (void)n_in; (void)out_size;
  const float* x     = (const float*)d_in[0];
  const int*   ei    = (const int*)d_in[1];
  const float* w1    = (const float*)d_in[2];
  const float* b1    = (const float*)d_in[3];
  const float* w2    = (const float*)d_in[4];
  const float* b2    = (const float*)d_in[5];
  const float* rootw = (const float*)d_in[6];
  const float* convb = (const float*)d_in[7];
  const float* advw  = (const float*)d_in[8];
  const float* advb  = (const float*)d_in[9];
  const float* v1w   = (const float*)d_in[10];
  const float* v1b   = (const float*)d_in[11];
  const float* v2w   = (const float*)d_in[12];
  const float* v2b   = (const float*)d_in[13];
  const float* v3w   = (const float*)d_in[14];
  const float* v3b   = (const float*)d_in[15];
  float* out = (float*)d_out;

  const size_t f0B = 131072;                    // feat0 64 KB (padded)
  const size_t wtB = (size_t)Ktot * CTOT * 2;   // 16.8 MB

  int NS = 64;
  while (NS > 8 && f0B + wtB + (size_t)NS * Bsz * CTOT * 4 > ws_size)
    NS >>= 1;

  unsigned short* feat0 = (unsigned short*)d_ws;
  unsigned short* wtp   = (unsigned short*)((char*)d_ws + f0B);
  float* part = (float*)((char*)d_ws + f0B + wtB);

  prep_feat_kernel<<<1040, 256, 0, stream>>>(x, ei, w1, b1, w2, b2, rootw,
                                             convb, advw, v1w, wtp, feat0);
  gemm_mfma<<<dim3(NS, 8), 512, 0, stream>>>(x, wtp, rootw, convb, feat0, part,
                                             1024 / NS, NS);
  final_kernel<<<Bsz, 256, 0, stream>>>(part, NS, advb, v1b, v2w, v2b, v3w, v3b, out);
}

// Round 13
// 165.543 us; speedup vs baseline: 1.0121x; 1.0052x over previous
//
#include <hip/hip_runtime.h>

#define Bsz 1024
#define Nn 256
#define Fdim 8
#define Eedge 1024
#define OUTC 128
#define CADV 192
#define CTOT 256
#define Ktot 32768   // Nn * OUTC
#define ASTR 40      // a_s/b_s LDS row stride in bf16 (32+8): 16B-aligned
#define XSTR 24      // x_s/rw_s row stride (48 B = 12-bank stride -> 2-way, free)

typedef __attribute__((ext_vector_type(8))) short short8;
typedef __attribute__((ext_vector_type(4))) float float4v;

static __device__ inline unsigned short f2bf(float f) {
  union { float f; unsigned u; } v; v.f = f;
  unsigned r = v.u + 0x7FFFu + ((v.u >> 16) & 1u);  // round-nearest-even
  return (unsigned short)(r >> 16);
}
static __device__ inline float bf2f(unsigned short h) {
  union { unsigned u; float f; } v; v.u = ((unsigned)h) << 16;
  return v.f;
}
static __device__ inline uint4 pack8(const unsigned short* b) {
  uint4 v;
  v.x = (unsigned)b[0] | ((unsigned)b[1] << 16);
  v.y = (unsigned)b[2] | ((unsigned)b[3] << 16);
  v.z = (unsigned)b[4] | ((unsigned)b[5] << 16);
  v.w = (unsigned)b[6] | ((unsigned)b[7] << 16);
  return v;
}
// HW packed f32->bf16 RNE convert: dst = bf(a) | bf(b)<<16, ONE VALU op.
static __device__ inline unsigned cvtpk(float a, float b) {
  unsigned r;
  asm("v_cvt_pk_bf16_f32 %0, %1, %2" : "=v"(r) : "v"(a), "v"(b));
  return r;
}
static __device__ inline float hi_of(unsigned p)  {  // bf2f(low half)
  union { unsigned u; float f; } v; v.u = p << 16; return v.f;
}
static __device__ inline float hi2_of(unsigned p) {  // bf2f(high half)
  union { unsigned u; float f; } v; v.u = p & 0xFFFF0000u; return v.f;
}

// ---------------------------------------------------------------------------
// K1 (R13-proven): tail x16 (theta + S scatter + feat0 b=0 correction)
// + wt transpose (linear layout; K2 LDS-stages it).
// ---------------------------------------------------------------------------
__global__ __launch_bounds__(256) void prep_feat_kernel(
    const float* __restrict__ x, const int* __restrict__ ei,
    const float* __restrict__ w1, const float* __restrict__ b1,
    const float* __restrict__ w2, const float* __restrict__ b2,
    const float* __restrict__ rootw, const float* __restrict__ convb,
    const float* __restrict__ advw, const float* __restrict__ v1w,
    unsigned short* __restrict__ wt, unsigned short* __restrict__ feat0)
{
  __shared__ __align__(16) char smem[20480];
  int bid = blockIdx.x, t = threadIdx.x;

  if (bid < 16) {
    // ---- tail x16: theta slice + redundant scatter S + feat0 o-slice ----
    float* fs   = (float*)smem;
    float* h_s  = fs;            // 64
    float* rw_s = fs + 64;       // 64
    float* th_s = fs + 128;      // 64
    float* pt_s = fs + 192;      // 256
    float* S_s  = fs + 448;      // 2048
    int*   flag = (int*)(fs + 2496);
    int obase = bid * 8;

    if (t < 64) {
      h_s[t]  = fmaxf(w1[t] + b1[t], 0.f);
      rw_s[t] = rootw[(t >> 3) * OUTC + obase + (t & 7)];
    }
    for (int i = t; i < Nn * Fdim; i += 256) S_s[i] = 0.f;
    if (t == 0) {
      int z = 0;
      for (int i = 1; i < 16; i += 2) z |= ei[i];
      *flag = (z == 0);  // little-endian int64 detection
    }
    __syncthreads();
    int is64 = *flag;

    {  // theta slice: 64 cols x 64-deep reduction across 4 waves
      int l = t & 63, g = t >> 6;
      int c = (l >> 3) * 128 + obase + (l & 7);
      float p = 0.f;
#pragma unroll
      for (int j = 0; j < 16; ++j)
        p += h_s[g * 16 + j] * w2[(size_t)(g * 16 + j) * 1024 + c];
      pt_s[t] = p;
    }
    int srcs[4], tgts[4];
#pragma unroll
    for (int q = 0; q < 4; ++q) {
      int e = t + q * 256;
      if (is64) { srcs[q] = ei[2 * e]; tgts[q] = ei[2 * (Eedge + e)]; }
      else      { srcs[q] = ei[e];     tgts[q] = ei[Eedge + e]; }
      srcs[q] &= 255; tgts[q] &= 255;
    }
    __syncthreads();
    if (t < 64) {
      int c = (t >> 3) * 128 + obase + (t & 7);
      th_s[t] = b2[c] + pt_s[t] + pt_s[t + 64] + pt_s[t + 128] + pt_s[t + 192];
    }
#pragma unroll
    for (int q = 0; q < 4; ++q) {
      const float* xp = x + srcs[q] * Fdim;
#pragma unroll
      for (int f = 0; f < Fdim; ++f)
        atomicAdd(&S_s[tgts[q] * Fdim + f], xp[f]);
    }
    __syncthreads();
    {  // feat0 slice: thread t = node n, 8 o-columns
      int n = t;
      const float* xp = x + n * Fdim;
      float4 xa = *(const float4*)xp;
      float4 xb = *(const float4*)(xp + 4);
      float xv[8] = {xa.x, xa.y, xa.z, xa.w, xb.x, xb.y, xb.z, xb.w};
      float sv[8];
#pragma unroll
      for (int f = 0; f < 8; ++f) sv[f] = S_s[n * Fdim + f];
      unsigned short buf[8];
#pragma unroll
      for (int oi = 0; oi < 8; ++oi) {
        float z = convb[obase + oi];
#pragma unroll
        for (int f = 0; f < 8; ++f)
          z += xv[f] * rw_s[f * 8 + oi] + sv[f] * th_s[f * 8 + oi];
        buf[oi] = f2bf(fmaxf(z, 0.f));
      }
      *(uint4*)(feat0 + (size_t)n * OUTC + obase) = pack8(buf);
    }
  } else {
    // ---- wt transpose: 32-deep load batch, LDS-staged, coalesced flush ----
    unsigned short* st = (unsigned short*)smem;  // 20 KB
    int kt = bid - 16, c = t;
    const float* src; int stride, col;
    if (c < CADV) { src = advw; stride = CADV; col = c; }
    else          { src = v1w;  stride = 64;   col = c - CADV; }
    float v[32];
#pragma unroll
    for (int i = 0; i < 32; ++i)
      v[i] = src[(size_t)(kt * 32 + i) * stride + col];
    unsigned pk[16];
#pragma unroll
    for (int i = 0; i < 16; ++i) pk[i] = cvtpk(v[2 * i], v[2 * i + 1]);
#pragma unroll
    for (int p = 0; p < 4; ++p) {
      uint4 w4; w4.x = pk[p * 4]; w4.y = pk[p * 4 + 1];
      w4.z = pk[p * 4 + 2]; w4.w = pk[p * 4 + 3];
      *(uint4*)(st + c * ASTR + p * 8) = w4;
    }
    __syncthreads();
    uint4* dst = (uint4*)(wt + (size_t)kt * (CTOT * 32));
    for (int r = 0; r < 4; ++r) {
      int s = r * 256 + c;        // lane-consecutive -> coalesced
      dst[s] = *(const uint4*)(st + (s >> 2) * ASTR + (s & 3) * 8);
    }
  }
}

// ---------------------------------------------------------------------------
// K2 (R22): R13/R19-proven dataflow, re-parameterized mb=16 x NS=32.
// Invariant analysis (R17 post-mortem): total B-LDS-staging = blocks x iters
// x 16KB. R13: 512x16 = 131 MB; this config: 512x16 = SAME (R17's 512x64 =
// 524 MB was the regression). A-gen volume, barrier count, 2 blocks/CU all
// identical to R13. The only delta: part halves 64 -> 32 MB (gemm write and
// K3 read each save 32 MB of pure intermediate HBM traffic).
// BM=64 rows/block, BN=256, BK=32, iters=32, 8 nodes/chunk.
// Grid dim3(32, 16): XCD = ch%8 (32%8==0), 16 mb-blocks share each chunk's
// wt slabs (~2-3 MB/XCD working set, L2-resident).
// ---------------------------------------------------------------------------
__global__ __launch_bounds__(512, 2) void gemm_mfma(
    const float* __restrict__ x, const unsigned short* __restrict__ wt,
    const float* __restrict__ rootw, const float* __restrict__ convb,
    const unsigned short* __restrict__ feat0, float* __restrict__ part,
    int iters, int ns)
{
  __shared__ short a_s[2][64 * ASTR];    // 10 KB
  __shared__ short b_s[2][256 * ASTR];   // 40 KB
  __shared__ short x_s[2][64 * XSTR];    // 6 KB  [b][xh0..7 | xl0..7 | pad]
  __shared__ short rw_s[128 * XSTR];     // 6 KB  [o][wh0..7 | wl0..7 | pad]
  __shared__ float convb_s[128];         // 0.5 KB
  int t = threadIdx.x;
  int ch = blockIdx.x;   // K chunk (XCD = ch%8)
  int mb = blockIdx.y;   // 0..15
  int wave = t >> 6, lane = t & 63;
  int wm = wave >> 2, wn = wave & 3;   // 2 x 4 wave grid over 64x256 tile
  int lm = lane & 15, lq = lane >> 4;

  float4v acc[2][4];
#pragma unroll
  for (int i = 0; i < 2; ++i)
#pragma unroll
    for (int j = 0; j < 4; ++j) acc[i][j] = (float4v)0.f;

  int kt0 = ch * iters;
  int iters4 = iters >> 2;          // nodes in this chunk (8)
  int n0 = ch * iters4;             // first node
  int wr0 = (t >> 2) * ASTR + (t & 3) * 8;
  int u1 = t + 512;
  int wr1 = (u1 >> 2) * ASTR + (u1 & 3) * 8;
  int grow = (wave & 3) * 16 + lm;  // A-gen batch row (0..63)
  int gtt  = wave >> 2;             // A-gen o-subtile within slab (0..1)

  // ---- prologue staging ----
  if (t < 128) {
    float wv[8];
#pragma unroll
    for (int f = 0; f < 8; ++f) wv[f] = rootw[f * OUTC + t];
    unsigned ph[4];
#pragma unroll
    for (int i = 0; i < 4; ++i) ph[i] = cvtpk(wv[2 * i], wv[2 * i + 1]);
    float wl[8];
#pragma unroll
    for (int i = 0; i < 4; ++i) {
      wl[2 * i]     = wv[2 * i]     - hi_of(ph[i]);
      wl[2 * i + 1] = wv[2 * i + 1] - hi2_of(ph[i]);
    }
    unsigned pl[4];
#pragma unroll
    for (int i = 0; i < 4; ++i) pl[i] = cvtpk(wl[2 * i], wl[2 * i + 1]);
    uint4 wh4; wh4.x = ph[0]; wh4.y = ph[1]; wh4.z = ph[2]; wh4.w = ph[3];
    uint4 wl4; wl4.x = pl[0]; wl4.y = pl[1]; wl4.z = pl[2]; wl4.w = pl[3];
    *(uint4*)(rw_s + t * XSTR)     = wh4;
    *(uint4*)(rw_s + t * XSTR + 8) = wl4;
    convb_s[t] = convb[t];
  }
  int xr = (t & 127) >> 1, xh = t & 1;
  const float* xgb = x + ((size_t)(mb * 64 + xr) * Nn) * Fdim + xh * 4;
  if (t < 128) {
    float4 xv = *(const float4*)(xgb + (size_t)n0 * Fdim);
    uint2 dh, dl;
    dh.x = cvtpk(xv.x, xv.y);
    dh.y = cvtpk(xv.z, xv.w);
    dl.x = cvtpk(xv.x - hi_of(dh.x), xv.y - hi2_of(dh.x));
    dl.y = cvtpk(xv.z - hi_of(dh.y), xv.w - hi2_of(dh.y));
    *(uint2*)(x_s[0] + xr * XSTR + xh * 4)     = dh;
    *(uint2*)(x_s[0] + xr * XSTR + 8 + xh * 4) = dl;
  }
  __syncthreads();

  // stage A-subtile for iter 0 (slab kt0: node n0, o-range [0,32)):
  // 8 waves x 1 gen-MFMA (4 row-groups x 2 o-subtiles)
  {
    short8 xf = (short8)0;
    if (lq == 0 || lq == 2) xf = *(const short8*)(x_s[0] + grow * XSTR);
    else if (lq == 1)       xf = *(const short8*)(x_s[0] + grow * XSTR + 8);
    int ot = gtt;                        // kt0&3 == 0
    short8 wf = (short8)0;
    if (lq <= 1)      wf = *(const short8*)(rw_s + (ot * 16 + lm) * XSTR);
    else if (lq == 2) wf = *(const short8*)(rw_s + (ot * 16 + lm) * XSTR + 8);
    float4v c = __builtin_amdgcn_mfma_f32_16x16x32_bf16(wf, xf, (float4v)0.f, 0, 0, 0);
    int o0 = ot * 16 + lq * 4;
    float4 cb = *(const float4*)(convb_s + o0);
    unsigned d0 = cvtpk(fmaxf(c[0] + cb.x, 0.f), fmaxf(c[1] + cb.y, 0.f));
    unsigned d1 = cvtpk(fmaxf(c[2] + cb.z, 0.f), fmaxf(c[3] + cb.w, 0.f));
    if (mb == 0 && grow == 0) {
      const unsigned* f0p = (const unsigned*)(feat0 + ((size_t)n0 * OUTC + o0));
      d0 = f0p[0]; d1 = f0p[1];
    }
    uint2 dd; dd.x = d0; dd.y = d1;
    *(uint2*)(a_s[0] + grow * ASTR + gtt * 16 + lq * 4) = dd;
  }

  // preload B tile 0
  const uint4* gB = (const uint4*)wt + (size_t)kt0 * 1024;
  uint4 vb0 = gB[t], vb1 = gB[t + 512];
  float4 xpf = {0.f, 0.f, 0.f, 0.f};

  for (int kk = 0; kk < iters; ++kk) {
    int g = kk & 3, grp = kk >> 2;
    short* bb = b_s[kk & 1];
    *(uint4*)(bb + wr0) = vb0;
    *(uint4*)(bb + wr1) = vb1;
    if (g == 0 && grp + 1 < iters4 && t < 128)
      xpf = *(const float4*)(xgb + (size_t)(n0 + grp + 1) * Fdim);
    if (g == 3 && grp + 1 < iters4 && t < 128) {
      uint2 dh, dl;
      dh.x = cvtpk(xpf.x, xpf.y);
      dh.y = cvtpk(xpf.z, xpf.w);
      dl.x = cvtpk(xpf.x - hi_of(dh.x), xpf.y - hi2_of(dh.x));
      dl.y = cvtpk(xpf.z - hi_of(dh.y), xpf.w - hi2_of(dh.y));
      short* xd = x_s[(grp + 1) & 1];
      *(uint2*)(xd + xr * XSTR + xh * 4)     = dh;
      *(uint2*)(xd + xr * XSTR + 8 + xh * 4) = dl;
    }
    if (kk + 1 < iters) {
      const uint4* gB2 = (const uint4*)wt + (size_t)(kt0 + kk + 1) * 1024;
      vb0 = gB2[t]; vb1 = gB2[t + 512];
    }
    __syncthreads();

    // main MFMA on tile kk
    short* ab = a_s[kk & 1];
    short8 aF[2];
#pragma unroll
    for (int i = 0; i < 2; ++i)
      aF[i] = *(const short8*)(ab + (wm * 32 + i * 16 + lm) * ASTR + lq * 8);
#pragma unroll
    for (int j = 0; j < 4; ++j) {
      short8 bF = *(const short8*)(bb + (wn * 64 + j * 16 + lm) * ASTR + lq * 8);
#pragma unroll
      for (int i = 0; i < 2; ++i)
        acc[i][j] = __builtin_amdgcn_mfma_f32_16x16x32_bf16(bF, aF[i], acc[i][j], 0, 0, 0);
    }

    // stage A-subtile for iter kk+1 into the other buffer (8 waves x 1)
    if (kk + 1 < iters) {
      int kn = kk + 1;
      int g2 = kn & 3, grp2 = kn >> 2;
      const short* xs = x_s[grp2 & 1];
      int node2 = n0 + grp2;
      short* ad = a_s[kn & 1];
      short8 xf = (short8)0;
      if (lq == 0 || lq == 2) xf = *(const short8*)(xs + grow * XSTR);
      else if (lq == 1)       xf = *(const short8*)(xs + grow * XSTR + 8);
      int ot = g2 * 2 + gtt;
      short8 wf = (short8)0;
      if (lq <= 1)      wf = *(const short8*)(rw_s + (ot * 16 + lm) * XSTR);
      else if (lq == 2) wf = *(const short8*)(rw_s + (ot * 16 + lm) * XSTR + 8);
      float4v c = __builtin_amdgcn_mfma_f32_16x16x32_bf16(wf, xf, (float4v)0.f, 0, 0, 0);
      int o0 = ot * 16 + lq * 4;
      float4 cb = *(const float4*)(convb_s + o0);
      unsigned d0 = cvtpk(fmaxf(c[0] + cb.x, 0.f), fmaxf(c[1] + cb.y, 0.f));
      unsigned d1 = cvtpk(fmaxf(c[2] + cb.z, 0.f), fmaxf(c[3] + cb.w, 0.f));
      if (mb == 0 && grow == 0) {
        const unsigned* f0p = (const unsigned*)(feat0 + ((size_t)node2 * OUTC + o0));
        d0 = f0p[0]; d1 = f0p[1];
      }
      uint2 dd; dd.x = d0; dd.y = d1;
      *(uint2*)(ad + grow * ASTR + gtt * 16 + lq * 4) = dd;
    }
  }

  // epilogue: part layout [b][ch][c]; per-lane dwordx4
  float* pb = part + ((size_t)(mb * 64) * ns + ch) * CTOT;
#pragma unroll
  for (int i = 0; i < 2; ++i) {
    int m = wm * 32 + i * 16 + lm;
#pragma unroll
    for (int j = 0; j < 4; ++j) {
      int c = wn * 64 + j * 16 + lq * 4;
      *(float4v*)(pb + (size_t)m * ns * CTOT + c) = acc[i][j];
    }
  }
}

// ---------------------------------------------------------------------------
// K3 (R19-proven): float4-vectorized split-K reduction + LDS combine,
// then biases+relu, val MLP, dueling combine. ns=32 -> 32 KB read/block.
// ---------------------------------------------------------------------------
__global__ __launch_bounds__(256) void final_kernel(
    const float* __restrict__ part, int ns,
    const float* __restrict__ advb, const float* __restrict__ v1b,
    const float* __restrict__ v2w, const float* __restrict__ v2b,
    const float* __restrict__ v3w, const float* __restrict__ v3b,
    float* __restrict__ out)
{
  __shared__ float4v red_s[4][64];   // 4 KB
  __shared__ float adv_s[CADV];
  __shared__ float v1_s[64];
  __shared__ float val2_s[64];
  __shared__ float val3_s[64];
  int b = blockIdx.x, t = threadIdx.x;
  int q = t & 63, r0 = t >> 6;       // col-quad, row-group
  const float4v* p4 = (const float4v*)(part + (size_t)b * ns * CTOT);
  float4v s4 = (float4v)0.f;
  for (int i = r0; i < ns; i += 4) s4 += p4[i * 64 + q];
  red_s[r0][q] = s4;
  __syncthreads();
  float s;
  {
    const float* rs = (const float*)red_s;   // [r][256] floats
    s = rs[t] + rs[256 + t] + rs[512 + t] + rs[768 + t];
  }
  if (t < CADV) adv_s[t] = fmaxf(s + advb[t], 0.f);
  else          v1_s[t - CADV] = fmaxf(s + v1b[t - CADV], 0.f);
  __syncthreads();
  if (t < 64) {
    float a = v2b[t];
#pragma unroll
    for (int i = 0; i < 64; ++i) a += v1_s[i] * v2w[i * 64 + t];
    val2_s[t] = fmaxf(a, 0.f);
  }
  __syncthreads();
  if (t < 64) {
    float a = v3b[t];
#pragma unroll
    for (int j = 0; j < 64; ++j) a += val2_s[j] * v3w[j * 64 + t];
    val3_s[t] = a;
  }
  __syncthreads();
  if (t < CADV) {
    int d = t / 3;
    float mean = (adv_s[d * 3] + adv_s[d * 3 + 1] + adv_s[d * 3 + 2]) * (1.f / 3.f);
    out[(size_t)b * CADV + t] = val3_s[d] + adv_s[t] - mean;
  }
}

extern "C" void kernel_launch(void* const* d_in, const int* in_sizes, int n_in,
                              void* d_out, int out_size, void* d_ws, size_t ws_size,
                              hipStream_t stream)
{
  (void)in_sizes; (void)n_in; (void)out_size;
  const float* x     = (const float*)d_in[0];
  const int*   ei    = (const int*)d_in[1];
  const float* w1    = (const float*)d_in[2];
  const float* b1    = (const float*)d_in[3];
  const float* w2    = (const float*)d_in[4];
  const float* b2    = (const float*)d_in[5];
  const float* rootw = (const float*)d_in[6];
  const float* convb = (const float*)d_in[7];
  const float* advw  = (const float*)d_in[8];
  const float* advb  = (const float*)d_in[9];
  const float* v1w   = (const float*)d_in[10];
  const float* v1b   = (const float*)d_in[11];
  const float* v2w   = (const float*)d_in[12];
  const float* v2b   = (const float*)d_in[13];
  const float* v3w   = (const float*)d_in[14];
  const float* v3b   = (const float*)d_in[15];
  float* out = (float*)d_out;

  const size_t f0B = 131072;                    // feat0 64 KB (padded)
  const size_t wtB = (size_t)Ktot * CTOT * 2;   // 16.8 MB

  int NS = 32;   // x 16 mb-blocks; part = 32 MB (ws >= 81 MB proven)
  while (NS > 8 && f0B + wtB + (size_t)NS * Bsz * CTOT * 4 > ws_size)
    NS >>= 1;

  unsigned short* feat0 = (unsigned short*)d_ws;
  unsigned short* wtp   = (unsigned short*)((char*)d_ws + f0B);
  float* part = (float*)((char*)d_ws + f0B + wtB);

  prep_feat_kernel<<<1040, 256, 0, stream>>>(x, ei, w1, b1, w2, b2, rootw,
                                             convb, advw, v1w, wtp, feat0);
  gemm_mfma<<<dim3(NS, 16), 512, 0, stream>>>(x, wtp, rootw, convb, feat0, part,
                                              1024 / NS, NS);
  final_kernel<<<Bsz, 256, 0, stream>>>(part, NS, advb, v1b, v2w, v2b, v3w, v3b, out);
}